// Round 1
// baseline (954.654 us; speedup 1.0000x reference)
//
#include <hip/hip_runtime.h>
#include <hip/hip_bf16.h>
#include <math.h>

#define TLEN 1024
#define HDIM 2048
#define NHEAD 32
#define HSZ 64
#define THE (TLEN * HDIM)

typedef __attribute__((ext_vector_type(8))) short bf16x8;
typedef __attribute__((ext_vector_type(4))) float f32x4;

__device__ __forceinline__ float waveRedSum(float v) {
#pragma unroll
  for (int off = 32; off > 0; off >>= 1) v += __shfl_xor(v, off, 64);
  return v;
}

__device__ __forceinline__ void gll16(const __hip_bfloat16* g, __hip_bfloat16* l) {
  __builtin_amdgcn_global_load_lds(
      (const __attribute__((address_space(1))) void*)g,
      (__attribute__((address_space(3))) void*)l, 16, 0, 0);
}

// ---------- weight convert + transpose: src f32 [R][C] -> dst bf16 [C][R] ----------
struct TrArgs {
  const float* src[8];
  __hip_bfloat16* dst[8];
  int R[8];
  int C[8];
};

__global__ __launch_bounds__(256) void transp_kernel(TrArgs ta) {
  const int z = blockIdx.z;
  const int R = ta.R[z], C = ta.C[z];
  const int c0 = blockIdx.x * 32, r0 = blockIdx.y * 32;
  if (c0 >= C || r0 >= R) return;
  __shared__ float tile[32][33];
  const int tx = threadIdx.x & 31, ty = threadIdx.x >> 5;
  const float* src = ta.src[z];
  __hip_bfloat16* dst = ta.dst[z];
#pragma unroll
  for (int i = 0; i < 4; i++)
    tile[ty + i * 8][tx] = src[(size_t)(r0 + ty + i * 8) * C + c0 + tx];
  __syncthreads();
#pragma unroll
  for (int i = 0; i < 4; i++)
    dst[(size_t)(c0 + ty + i * 8) * R + r0 + tx] = __float2bfloat16(tile[tx][ty + i * 8]);
}

// ---------- LayerNorm (row) + state1_out ----------
__global__ __launch_bounds__(256) void ln1_kernel(const float* __restrict__ x,
                                                  const float* __restrict__ w,
                                                  const float* __restrict__ b,
                                                  float* __restrict__ xl,
                                                  float* __restrict__ s1out) {
  const int t = blockIdx.x;
  const int tid = threadIdx.x;
  const int wid = tid >> 6, lane = tid & 63;
  const float4* xr = (const float4*)(x + (size_t)t * HDIM);
  float4 a = xr[tid];
  float4 c = xr[tid + 256];
  float va[8] = {a.x, a.y, a.z, a.w, c.x, c.y, c.z, c.w};
  float sum = 0.f;
#pragma unroll
  for (int i = 0; i < 8; i++) sum += va[i];
  sum = waveRedSum(sum);
  __shared__ float red[8];
  if (lane == 0) red[wid] = sum;
  __syncthreads();
  const float mu = (red[0] + red[1] + red[2] + red[3]) * (1.f / HDIM);
  float vs = 0.f;
#pragma unroll
  for (int i = 0; i < 8; i++) { float d = va[i] - mu; vs += d * d; }
  vs = waveRedSum(vs);
  if (lane == 0) red[4 + wid] = vs;
  __syncthreads();
  const float rstd = rsqrtf((red[4] + red[5] + red[6] + red[7]) * (1.f / HDIM) + 1e-5f);
  float* xrow = xl + (size_t)t * HDIM;
#pragma unroll
  for (int i = 0; i < 8; i++) {
    const int idx = (i < 4) ? (4 * tid + i) : (1024 + 4 * tid + (i - 4));
    const float o = (va[i] - mu) * rstd * w[idx] + b[idx];
    xrow[idx] = o;
    if (t == TLEN - 1) s1out[idx] = o;
  }
}

// ---------- token shift: xxx = xl + (past - xl) * time_maa_x ----------
__global__ __launch_bounds__(256) void tokshift_kernel(const float* __restrict__ xl,
                                                       const float* __restrict__ s1,
                                                       const float* __restrict__ tmx,
                                                       __hip_bfloat16* __restrict__ xxx) {
  const int t = blockIdx.x;
  const int h = blockIdx.y * 256 + threadIdx.x;
  const float cur = xl[(size_t)t * HDIM + h];
  const float past = (t > 0) ? xl[(size_t)(t - 1) * HDIM + h] : s1[h];
  xxx[(size_t)t * HDIM + h] = __float2bfloat16(cur + (past - cur) * tmx[h]);
}

// ---------- mix: x5[f] = xl + sx * (t5[f] @ w2[f] + time_maa[f]) ----------
__global__ __launch_bounds__(256) void mix_kernel(const float* __restrict__ t5,
                                                  const float* __restrict__ xl,
                                                  const float* __restrict__ s1,
                                                  const float* __restrict__ w2,
                                                  const float* __restrict__ maa,
                                                  __hip_bfloat16* __restrict__ x5b) {
  const int h = blockIdx.x * 256 + threadIdx.x;
  const int t0 = blockIdx.y * 8;
  __shared__ float t5L[8 * 160];
  for (int i = threadIdx.x; i < 8 * 160; i += 256) {
    const int rr = i / 160, cc = i - rr * 160;
    t5L[i] = t5[(size_t)(t0 + rr) * 160 + cc];
  }
  __syncthreads();
  float mixv[8][5];
#pragma unroll
  for (int ts = 0; ts < 8; ts++)
#pragma unroll
    for (int f = 0; f < 5; f++) mixv[ts][f] = 0.f;
#pragma unroll
  for (int f = 0; f < 5; f++) {
#pragma unroll 4
    for (int m = 0; m < 32; m++) {
      const float w2v = w2[(size_t)(f * 32 + m) * HDIM + h];
#pragma unroll
      for (int ts = 0; ts < 8; ts++) mixv[ts][f] += t5L[ts * 160 + f * 32 + m] * w2v;
    }
  }
#pragma unroll
  for (int ts = 0; ts < 8; ts++) {
    const int t = t0 + ts;
    const float cur = xl[(size_t)t * HDIM + h];
    const float past = (t > 0) ? xl[(size_t)(t - 1) * HDIM + h] : s1[h];
    const float sx = past - cur;
#pragma unroll
    for (int f = 0; f < 5; f++) {
      const float v = cur + sx * (mixv[ts][f] + maa[(size_t)f * HDIM + h]);
      x5b[(size_t)f * THE + (size_t)t * HDIM + h] = __float2bfloat16(v);
    }
  }
}

// ---------- batched MFMA GEMM: C[z] = epi( A[z](MxK) @ Bt[z](NxK)^T ) ----------
// epi: 0=bf16 none, 1=bf16 silu, 2=f32 tanh, 3=bf16 tanh, 4=f32 td(+p,clip,exp-exp), 5=f32 +residual
struct GemmArgs {
  const __hip_bfloat16* A[4];
  const __hip_bfloat16* B[4];
  void* C[4];
  const float* aux[4];
  int epi[4];
  int M, N, K;
};

__global__ __launch_bounds__(256) void gemm_bt(GemmArgs ga) {
  const int z = blockIdx.z;
  const __hip_bfloat16* __restrict__ A = ga.A[z];
  const __hip_bfloat16* __restrict__ Bt = ga.B[z];
  const int N = ga.N, K = ga.K;
  const int epi = ga.epi[z];
  const float* __restrict__ aux = ga.aux[z];
  void* Cz = ga.C[z];

  __shared__ __align__(16) __hip_bfloat16 As[128 * 32];
  __shared__ __align__(16) __hip_bfloat16 Bs[128 * 32];

  const int tid = threadIdx.x;
  const int wid = tid >> 6;
  const int lane = tid & 63;
  const int m0 = blockIdx.x * 128;
  const int n0 = blockIdx.y * 128;
  const int wr = wid >> 1, wc = wid & 1;

  const int rsub = lane >> 2;   // 0..15
  const int chunk = lane & 3;   // 0..3
  const int ca = 2 * wid;       // this wave's staging calls: ca, ca+1

  const int arow0 = ca * 16 + rsub;
  const int arow1 = arow0 + 16;
  int brow0 = n0 + arow0; if (brow0 > N - 1) brow0 = N - 1;
  int brow1 = n0 + arow1; if (brow1 > N - 1) brow1 = N - 1;

  const __hip_bfloat16* aSrc0 = A + (size_t)(m0 + arow0) * K + chunk * 8;
  const __hip_bfloat16* aSrc1 = A + (size_t)(m0 + arow1) * K + chunk * 8;
  const __hip_bfloat16* bSrc0 = Bt + (size_t)brow0 * K + chunk * 8;
  const __hip_bfloat16* bSrc1 = Bt + (size_t)brow1 * K + chunk * 8;

  f32x4 acc[4][4];
#pragma unroll
  for (int m = 0; m < 4; m++)
#pragma unroll
    for (int n = 0; n < 4; n++) acc[m][n] = 0.f;

  const int lr = lane & 15;
  const int lk8 = (lane >> 4) * 8;
  const int aoff = (wr * 64 + lr) * 32 + lk8;
  const int boff = (wc * 64 + lr) * 32 + lk8;

  for (int kt = 0; kt < K; kt += 32) {
    gll16(aSrc0 + kt, &As[ca * 512]);
    gll16(aSrc1 + kt, &As[ca * 512 + 512]);
    gll16(bSrc0 + kt, &Bs[ca * 512]);
    gll16(bSrc1 + kt, &Bs[ca * 512 + 512]);
    __syncthreads();
    bf16x8 af[4], bfv[4];
#pragma unroll
    for (int m = 0; m < 4; m++) af[m] = *(const bf16x8*)&As[aoff + m * 16 * 32];
#pragma unroll
    for (int n = 0; n < 4; n++) bfv[n] = *(const bf16x8*)&Bs[boff + n * 16 * 32];
#pragma unroll
    for (int m = 0; m < 4; m++)
#pragma unroll
      for (int n = 0; n < 4; n++)
        acc[m][n] = __builtin_amdgcn_mfma_f32_16x16x32_bf16(af[m], bfv[n], acc[m][n], 0, 0, 0);
    __syncthreads();
  }

  const int r4 = (lane >> 4) * 4;
#pragma unroll
  for (int m = 0; m < 4; m++) {
#pragma unroll
    for (int n = 0; n < 4; n++) {
      const int gn = n0 + wc * 64 + n * 16 + lr;
      if (gn < N) {
#pragma unroll
        for (int r = 0; r < 4; r++) {
          const int gm = m0 + wr * 64 + m * 16 + r4 + r;
          const size_t idx = (size_t)gm * N + gn;
          const float v = acc[m][n][r];
          switch (epi) {
            case 0: ((__hip_bfloat16*)Cz)[idx] = __float2bfloat16(v); break;
            case 1: ((__hip_bfloat16*)Cz)[idx] = __float2bfloat16(v / (1.f + expf(-v))); break;
            case 2: ((float*)Cz)[idx] = tanhf(v); break;
            case 3: ((__hip_bfloat16*)Cz)[idx] = __float2bfloat16(tanhf(v)); break;
            case 4: {
              float wv = v + aux[gn];
              wv = fminf(fmaxf(wv, -9.72f), 2.27f);
              ((float*)Cz)[idx] = expf(-expf(wv));
            } break;
            case 5: ((float*)Cz)[idx] = v + aux[idx]; break;
          }
        }
      }
    }
  }
}

// ---------- sequential scan: one 64-lane wave per (h, i) ----------
__global__ __launch_bounds__(64) void scan_kernel(const __hip_bfloat16* __restrict__ rb,
                                                  const __hip_bfloat16* __restrict__ kb,
                                                  const __hip_bfloat16* __restrict__ vb,
                                                  const float* __restrict__ td,
                                                  const float* __restrict__ s2in,
                                                  const float* __restrict__ tf,
                                                  float* __restrict__ wkv,
                                                  float* __restrict__ s2out) {
  const int i = blockIdx.x;   // 0..63
  const int h = blockIdx.y;   // 0..31
  const int j = threadIdx.x;  // 0..63
  float s = s2in[((size_t)h * HSZ + i) * HSZ + j];
  const float tfj = tf[h * HSZ + j];
  const int hb = h * HSZ;
  for (int t = 0; t < TLEN; t++) {
    const int base = t * HDIM + hb;
    const float rj = __bfloat162float(rb[base + j]);
    const float kj = __bfloat162float(kb[base + j]);
    const float vi = __bfloat162float(vb[base + i]);
    const float tdj = td[base + j];
    const float kv = vi * kj;
    float p = (kv * tfj + s) * rj;
    p = waveRedSum(p);
    if (j == 0) wkv[base + i] = p;
    s = s * tdj + kv;
  }
  s2out[((size_t)h * HSZ + i) * HSZ + j] = s;
}

// ---------- group norm over HS + scale/bias + gate ----------
__global__ __launch_bounds__(256) void gnorm_kernel(const float* __restrict__ wkv,
                                                    const __hip_bfloat16* __restrict__ gb,
                                                    const float* __restrict__ lnw,
                                                    const float* __restrict__ lnb,
                                                    __hip_bfloat16* __restrict__ yA) {
  const int t = blockIdx.x;
  const int wid = threadIdx.x >> 6, j = threadIdx.x & 63;
  const int h = blockIdx.y * 4 + wid;
  const size_t idx = (size_t)t * HDIM + h * HSZ + j;
  const float v = wkv[idx];
  const float mu = waveRedSum(v) * (1.f / HSZ);
  const float d = v - mu;
  const float var = waveRedSum(d * d) * (1.f / HSZ);
  float y = d * rsqrtf(var + 1e-5f);
  y = y * lnw[h * HSZ + j] + lnb[h * HSZ + j];
  y *= __bfloat162float(gb[idx]);
  yA[idx] = __float2bfloat16(y);
}

extern "C" void kernel_launch(void* const* d_in, const int* in_sizes, int n_in,
                              void* d_out, int out_size, void* d_ws, size_t ws_size,
                              hipStream_t stream) {
  (void)in_sizes; (void)n_in; (void)out_size; (void)ws_size;

  const float* x    = (const float*)d_in[0];
  const float* s1   = (const float*)d_in[1];
  const float* s2   = (const float*)d_in[2];
  const float* ln1w = (const float*)d_in[3];
  const float* ln1b = (const float*)d_in[4];
  const float* tmx  = (const float*)d_in[5];
  const float* tmaa = (const float*)d_in[6];
  const float* w1   = (const float*)d_in[7];
  const float* w2   = (const float*)d_in[8];
  const float* dw1  = (const float*)d_in[9];
  const float* dw2  = (const float*)d_in[10];
  const float* dp   = (const float*)d_in[11];
  const float* tf   = (const float*)d_in[12];
  const float* Wr   = (const float*)d_in[13];
  const float* Wk   = (const float*)d_in[14];
  const float* Wv   = (const float*)d_in[15];
  const float* Wg   = (const float*)d_in[16];
  const float* Wo   = (const float*)d_in[17];
  const float* lnxw = (const float*)d_in[18];
  const float* lnxb = (const float*)d_in[19];

  float* out0  = (float*)d_out;
  float* s1out = out0 + (size_t)TLEN * HDIM;
  float* s2out = s1out + HDIM;

  char* wp = (char*)d_ws;
  size_t off = 0;
  auto carve = [&](size_t bytes) -> void* {
    void* r = wp + off;
    off += (bytes + 255) & ~(size_t)255;
    return r;
  };

  __hip_bfloat16* wrt  = (__hip_bfloat16*)carve((size_t)HDIM * HDIM * 2);
  __hip_bfloat16* wkt  = (__hip_bfloat16*)carve((size_t)HDIM * HDIM * 2);
  __hip_bfloat16* wvt  = (__hip_bfloat16*)carve((size_t)HDIM * HDIM * 2);
  __hip_bfloat16* wgt  = (__hip_bfloat16*)carve((size_t)HDIM * HDIM * 2);
  __hip_bfloat16* wot  = (__hip_bfloat16*)carve((size_t)HDIM * HDIM * 2);
  __hip_bfloat16* w1t  = (__hip_bfloat16*)carve((size_t)160 * HDIM * 2);
  __hip_bfloat16* dw1t = (__hip_bfloat16*)carve((size_t)64 * HDIM * 2);
  __hip_bfloat16* dw2t = (__hip_bfloat16*)carve((size_t)HDIM * 64 * 2);
  float* xl            = (float*)carve((size_t)THE * 4);
  __hip_bfloat16* xxx  = (__hip_bfloat16*)carve((size_t)THE * 2);
  float* t5            = (float*)carve((size_t)TLEN * 160 * 4);
  __hip_bfloat16* x5b  = (__hip_bfloat16*)carve((size_t)5 * THE * 2);
  __hip_bfloat16* rb   = (__hip_bfloat16*)carve((size_t)THE * 2);
  __hip_bfloat16* kb   = (__hip_bfloat16*)carve((size_t)THE * 2);
  __hip_bfloat16* vb   = (__hip_bfloat16*)carve((size_t)THE * 2);
  __hip_bfloat16* gb   = (__hip_bfloat16*)carve((size_t)THE * 2);
  __hip_bfloat16* tw   = (__hip_bfloat16*)carve((size_t)TLEN * 64 * 2);
  float* td            = (float*)carve((size_t)THE * 4);
  float* wkv           = (float*)carve((size_t)THE * 4);
  __hip_bfloat16* yA   = (__hip_bfloat16*)carve((size_t)THE * 2);

  // K0: convert + transpose all GEMM weights to bf16 [N][K]
  TrArgs ta;
  const float* srcs[8] = {Wr, Wk, Wv, Wg, Wo, w1, dw1, dw2};
  __hip_bfloat16* dsts[8] = {wrt, wkt, wvt, wgt, wot, w1t, dw1t, dw2t};
  const int Rs[8] = {HDIM, HDIM, HDIM, HDIM, HDIM, HDIM, HDIM, 64};
  const int Cs[8] = {HDIM, HDIM, HDIM, HDIM, HDIM, 160, 64, HDIM};
  for (int z = 0; z < 8; z++) { ta.src[z] = srcs[z]; ta.dst[z] = dsts[z]; ta.R[z] = Rs[z]; ta.C[z] = Cs[z]; }
  transp_kernel<<<dim3(64, 64, 8), 256, 0, stream>>>(ta);

  // K1: layernorm
  ln1_kernel<<<dim3(TLEN), 256, 0, stream>>>(x, ln1w, ln1b, xl, s1out);

  // K2: token shift -> xxx (bf16)
  tokshift_kernel<<<dim3(TLEN, HDIM / 256), 256, 0, stream>>>(xl, s1, tmx, xxx);

  // G1: t5 = tanh(xxx @ w1)  (M=1024, N=160, K=2048)
  {
    GemmArgs g{};
    g.A[0] = xxx; g.B[0] = w1t; g.C[0] = t5; g.aux[0] = nullptr; g.epi[0] = 2;
    g.M = TLEN; g.N = 160; g.K = HDIM;
    gemm_bt<<<dim3(TLEN / 128, 2, 1), 256, 0, stream>>>(g);
  }

  // K4: mix + x5 (5 planes, bf16)
  mix_kernel<<<dim3(HDIM / 256, TLEN / 8), 256, 0, stream>>>(t5, xl, s1, w2, tmaa, x5b);

  // G2: r, k, v, g  (batched z=4)
  {
    GemmArgs g{};
    g.A[0] = x5b + (size_t)3 * THE; g.B[0] = wrt; g.C[0] = rb; g.epi[0] = 0;
    g.A[1] = x5b + (size_t)1 * THE; g.B[1] = wkt; g.C[1] = kb; g.epi[1] = 0;
    g.A[2] = x5b + (size_t)2 * THE; g.B[2] = wvt; g.C[2] = vb; g.epi[2] = 0;
    g.A[3] = x5b + (size_t)4 * THE; g.B[3] = wgt; g.C[3] = gb; g.epi[3] = 1;
    g.M = TLEN; g.N = HDIM; g.K = HDIM;
    gemm_bt<<<dim3(TLEN / 128, HDIM / 128, 4), 256, 0, stream>>>(g);
  }

  // G4: tw = tanh(mw @ dw1)  (N=64)
  {
    GemmArgs g{};
    g.A[0] = x5b; g.B[0] = dw1t; g.C[0] = tw; g.epi[0] = 3;
    g.M = TLEN; g.N = 64; g.K = HDIM;
    gemm_bt<<<dim3(TLEN / 128, 1, 1), 256, 0, stream>>>(g);
  }

  // G5: td = exp(-exp(clip(tw @ dw2 + p)))  (K=64)
  {
    GemmArgs g{};
    g.A[0] = tw; g.B[0] = dw2t; g.C[0] = td; g.aux[0] = dp; g.epi[0] = 4;
    g.M = TLEN; g.N = HDIM; g.K = 64;
    gemm_bt<<<dim3(TLEN / 128, HDIM / 128, 1), 256, 0, stream>>>(g);
  }

  // K6: recurrent scan
  scan_kernel<<<dim3(HSZ, NHEAD), 64, 0, stream>>>(rb, kb, vb, td, s2, tf, wkv, s2out);

  // K7: group-norm + gate -> yA (bf16)
  gnorm_kernel<<<dim3(TLEN, NHEAD / 4), 256, 0, stream>>>(wkv, gb, lnxw, lnxb, yA);

  // G6: out = x + yA @ W_o
  {
    GemmArgs g{};
    g.A[0] = yA; g.B[0] = wot; g.C[0] = out0; g.aux[0] = x; g.epi[0] = 5;
    g.M = TLEN; g.N = HDIM; g.K = HDIM;
    gemm_bt<<<dim3(TLEN / 128, HDIM / 128, 1), 256, 0, stream>>>(g);
  }
}

// Round 2
// 522.862 us; speedup vs baseline: 1.8258x; 1.8258x over previous
//
#include <hip/hip_runtime.h>
#include <hip/hip_bf16.h>
#include <math.h>

#define TLEN 1024
#define HDIM 2048
#define NHEAD 32
#define HSZ 64
#define THE (TLEN * HDIM)

typedef __attribute__((ext_vector_type(8))) short bf16x8;
typedef __attribute__((ext_vector_type(4))) float f32x4;

__device__ __forceinline__ float waveRedSum(float v) {
#pragma unroll
  for (int off = 32; off > 0; off >>= 1) v += __shfl_xor(v, off, 64);
  return v;
}

__device__ __forceinline__ void gll16(const __hip_bfloat16* g, __hip_bfloat16* l) {
  __builtin_amdgcn_global_load_lds(
      (const __attribute__((address_space(1))) void*)g,
      (__attribute__((address_space(3))) void*)l, 16, 0, 0);
}

// ---------- weight convert + transpose: src f32 [R][C] -> dst bf16 [C][R] ----------
struct TrArgs {
  const float* src[8];
  __hip_bfloat16* dst[8];
  int R[8];
  int C[8];
};

__global__ __launch_bounds__(256) void transp_kernel(TrArgs ta) {
  const int z = blockIdx.z;
  const int R = ta.R[z], C = ta.C[z];
  const int c0 = blockIdx.x * 32, r0 = blockIdx.y * 32;
  if (c0 >= C || r0 >= R) return;
  __shared__ float tile[32][33];
  const int tx = threadIdx.x & 31, ty = threadIdx.x >> 5;
  const float* src = ta.src[z];
  __hip_bfloat16* dst = ta.dst[z];
#pragma unroll
  for (int i = 0; i < 4; i++)
    tile[ty + i * 8][tx] = src[(size_t)(r0 + ty + i * 8) * C + c0 + tx];
  __syncthreads();
#pragma unroll
  for (int i = 0; i < 4; i++)
    dst[(size_t)(c0 + ty + i * 8) * R + r0 + tx] = __float2bfloat16(tile[tx][ty + i * 8]);
}

// ---------- LayerNorm (row) + state1_out ----------
__global__ __launch_bounds__(256) void ln1_kernel(const float* __restrict__ x,
                                                  const float* __restrict__ w,
                                                  const float* __restrict__ b,
                                                  float* __restrict__ xl,
                                                  float* __restrict__ s1out) {
  const int t = blockIdx.x;
  const int tid = threadIdx.x;
  const int wid = tid >> 6, lane = tid & 63;
  const float4* xr = (const float4*)(x + (size_t)t * HDIM);
  float4 a = xr[tid];
  float4 c = xr[tid + 256];
  float va[8] = {a.x, a.y, a.z, a.w, c.x, c.y, c.z, c.w};
  float sum = 0.f;
#pragma unroll
  for (int i = 0; i < 8; i++) sum += va[i];
  sum = waveRedSum(sum);
  __shared__ float red[8];
  if (lane == 0) red[wid] = sum;
  __syncthreads();
  const float mu = (red[0] + red[1] + red[2] + red[3]) * (1.f / HDIM);
  float vs = 0.f;
#pragma unroll
  for (int i = 0; i < 8; i++) { float d = va[i] - mu; vs += d * d; }
  vs = waveRedSum(vs);
  if (lane == 0) red[4 + wid] = vs;
  __syncthreads();
  const float rstd = rsqrtf((red[4] + red[5] + red[6] + red[7]) * (1.f / HDIM) + 1e-5f);
  float* xrow = xl + (size_t)t * HDIM;
#pragma unroll
  for (int i = 0; i < 8; i++) {
    const int idx = (i < 4) ? (4 * tid + i) : (1024 + 4 * tid + (i - 4));
    const float o = (va[i] - mu) * rstd * w[idx] + b[idx];
    xrow[idx] = o;
    if (t == TLEN - 1) s1out[idx] = o;
  }
}

// ---------- token shift: xxx = xl + (past - xl) * time_maa_x ----------
__global__ __launch_bounds__(256) void tokshift_kernel(const float* __restrict__ xl,
                                                       const float* __restrict__ s1,
                                                       const float* __restrict__ tmx,
                                                       __hip_bfloat16* __restrict__ xxx) {
  const int t = blockIdx.x;
  const int h = blockIdx.y * 256 + threadIdx.x;
  const float cur = xl[(size_t)t * HDIM + h];
  const float past = (t > 0) ? xl[(size_t)(t - 1) * HDIM + h] : s1[h];
  xxx[(size_t)t * HDIM + h] = __float2bfloat16(cur + (past - cur) * tmx[h]);
}

// ---------- mix: x5[f] = xl + sx * (t5[f] @ w2[f] + time_maa[f]) ----------
__global__ __launch_bounds__(256) void mix_kernel(const float* __restrict__ t5,
                                                  const float* __restrict__ xl,
                                                  const float* __restrict__ s1,
                                                  const float* __restrict__ w2,
                                                  const float* __restrict__ maa,
                                                  __hip_bfloat16* __restrict__ x5b) {
  const int h = blockIdx.x * 256 + threadIdx.x;
  const int t0 = blockIdx.y * 8;
  __shared__ float t5L[8 * 160];
  for (int i = threadIdx.x; i < 8 * 160; i += 256) {
    const int rr = i / 160, cc = i - rr * 160;
    t5L[i] = t5[(size_t)(t0 + rr) * 160 + cc];
  }
  __syncthreads();
  float mixv[8][5];
#pragma unroll
  for (int ts = 0; ts < 8; ts++)
#pragma unroll
    for (int f = 0; f < 5; f++) mixv[ts][f] = 0.f;
#pragma unroll
  for (int f = 0; f < 5; f++) {
#pragma unroll 4
    for (int m = 0; m < 32; m++) {
      const float w2v = w2[(size_t)(f * 32 + m) * HDIM + h];
#pragma unroll
      for (int ts = 0; ts < 8; ts++) mixv[ts][f] += t5L[ts * 160 + f * 32 + m] * w2v;
    }
  }
#pragma unroll
  for (int ts = 0; ts < 8; ts++) {
    const int t = t0 + ts;
    const float cur = xl[(size_t)t * HDIM + h];
    const float past = (t > 0) ? xl[(size_t)(t - 1) * HDIM + h] : s1[h];
    const float sx = past - cur;
#pragma unroll
    for (int f = 0; f < 5; f++) {
      const float v = cur + sx * (mixv[ts][f] + maa[(size_t)f * HDIM + h]);
      x5b[(size_t)f * THE + (size_t)t * HDIM + h] = __float2bfloat16(v);
    }
  }
}

// ---------- batched MFMA GEMM: C[z] = epi( A[z](MxK) @ Bt[z](NxK)^T ) ----------
// epi: 0=bf16 none, 1=bf16 silu, 2=f32 tanh, 3=bf16 tanh, 4=f32 td(+p,clip,exp-exp), 5=f32 +residual
struct GemmArgs {
  const __hip_bfloat16* A[4];
  const __hip_bfloat16* B[4];
  void* C[4];
  const float* aux[4];
  int epi[4];
  int M, N, K;
};

__global__ __launch_bounds__(256) void gemm_bt(GemmArgs ga) {
  const int z = blockIdx.z;
  const __hip_bfloat16* __restrict__ A = ga.A[z];
  const __hip_bfloat16* __restrict__ Bt = ga.B[z];
  const int N = ga.N, K = ga.K;
  const int epi = ga.epi[z];
  const float* __restrict__ aux = ga.aux[z];
  void* Cz = ga.C[z];

  __shared__ __align__(16) __hip_bfloat16 As[128 * 32];
  __shared__ __align__(16) __hip_bfloat16 Bs[128 * 32];

  const int tid = threadIdx.x;
  const int wid = tid >> 6;
  const int lane = tid & 63;
  const int m0 = blockIdx.x * 128;
  const int n0 = blockIdx.y * 128;
  const int wr = wid >> 1, wc = wid & 1;

  const int rsub = lane >> 2;   // 0..15
  const int chunk = lane & 3;   // 0..3
  const int ca = 2 * wid;       // this wave's staging calls: ca, ca+1

  const int arow0 = ca * 16 + rsub;
  const int arow1 = arow0 + 16;
  int brow0 = n0 + arow0; if (brow0 > N - 1) brow0 = N - 1;
  int brow1 = n0 + arow1; if (brow1 > N - 1) brow1 = N - 1;

  const __hip_bfloat16* aSrc0 = A + (size_t)(m0 + arow0) * K + chunk * 8;
  const __hip_bfloat16* aSrc1 = A + (size_t)(m0 + arow1) * K + chunk * 8;
  const __hip_bfloat16* bSrc0 = Bt + (size_t)brow0 * K + chunk * 8;
  const __hip_bfloat16* bSrc1 = Bt + (size_t)brow1 * K + chunk * 8;

  f32x4 acc[4][4];
#pragma unroll
  for (int m = 0; m < 4; m++)
#pragma unroll
    for (int n = 0; n < 4; n++) acc[m][n] = 0.f;

  const int lr = lane & 15;
  const int lk8 = (lane >> 4) * 8;
  const int aoff = (wr * 64 + lr) * 32 + lk8;
  const int boff = (wc * 64 + lr) * 32 + lk8;

  for (int kt = 0; kt < K; kt += 32) {
    gll16(aSrc0 + kt, &As[ca * 512]);
    gll16(aSrc1 + kt, &As[ca * 512 + 512]);
    gll16(bSrc0 + kt, &Bs[ca * 512]);
    gll16(bSrc1 + kt, &Bs[ca * 512 + 512]);
    __syncthreads();
    bf16x8 af[4], bfv[4];
#pragma unroll
    for (int m = 0; m < 4; m++) af[m] = *(const bf16x8*)&As[aoff + m * 16 * 32];
#pragma unroll
    for (int n = 0; n < 4; n++) bfv[n] = *(const bf16x8*)&Bs[boff + n * 16 * 32];
#pragma unroll
    for (int m = 0; m < 4; m++)
#pragma unroll
      for (int n = 0; n < 4; n++)
        acc[m][n] = __builtin_amdgcn_mfma_f32_16x16x32_bf16(af[m], bfv[n], acc[m][n], 0, 0, 0);
    __syncthreads();
  }

  const int r4 = (lane >> 4) * 4;
#pragma unroll
  for (int m = 0; m < 4; m++) {
#pragma unroll
    for (int n = 0; n < 4; n++) {
      const int gn = n0 + wc * 64 + n * 16 + lr;
      if (gn < N) {
#pragma unroll
        for (int r = 0; r < 4; r++) {
          const int gm = m0 + wr * 64 + m * 16 + r4 + r;
          const size_t idx = (size_t)gm * N + gn;
          const float v = acc[m][n][r];
          switch (epi) {
            case 0: ((__hip_bfloat16*)Cz)[idx] = __float2bfloat16(v); break;
            case 1: ((__hip_bfloat16*)Cz)[idx] = __float2bfloat16(v / (1.f + expf(-v))); break;
            case 2: ((float*)Cz)[idx] = tanhf(v); break;
            case 3: ((__hip_bfloat16*)Cz)[idx] = __float2bfloat16(tanhf(v)); break;
            case 4: {
              float wv = v + aux[gn];
              wv = fminf(fmaxf(wv, -9.72f), 2.27f);
              ((float*)Cz)[idx] = expf(-expf(wv));
            } break;
            case 5: ((float*)Cz)[idx] = v + aux[idx]; break;
          }
        }
      }
    }
  }
}

// ---------- repack k,r,td into 8B records: pk[h][t][j] = {k|r<<16, td} ----------
__global__ __launch_bounds__(256) void repack_kernel(const __hip_bfloat16* __restrict__ kb,
                                                     const __hip_bfloat16* __restrict__ rb,
                                                     const float* __restrict__ td,
                                                     uint2* __restrict__ pk) {
  const int idx = blockIdx.x * 256 + threadIdx.x;  // [h][t][j]
  const int j = idx & 63;
  const int t = (idx >> 6) & (TLEN - 1);
  const int h = idx >> 16;
  const size_t src = (size_t)t * HDIM + h * HSZ + j;
  uint2 o;
  const unsigned kk = *(const unsigned short*)&kb[src];
  const unsigned rr = *(const unsigned short*)&rb[src];
  o.x = kk | (rr << 16);
  o.y = __builtin_bit_cast(unsigned, td[src]);
  pk[idx] = o;
}

// ---------- v transpose: vb [TLEN][HDIM] bf16 -> vt [HDIM][TLEN] bf16 ----------
__global__ __launch_bounds__(256) void vtr_kernel(const __hip_bfloat16* __restrict__ vb,
                                                  __hip_bfloat16* __restrict__ vt) {
  __shared__ unsigned short tile[32][33];
  const int c0 = blockIdx.x * 32;  // HDIM
  const int r0 = blockIdx.y * 32;  // TLEN
  const int tx = threadIdx.x & 31, ty = threadIdx.x >> 5;
#pragma unroll
  for (int i = 0; i < 4; i++)
    tile[ty + i * 8][tx] = *(const unsigned short*)&vb[(size_t)(r0 + ty + i * 8) * HDIM + c0 + tx];
  __syncthreads();
#pragma unroll
  for (int i = 0; i < 4; i++)
    *(unsigned short*)&vt[(size_t)(c0 + ty + i * 8) * TLEN + r0 + tx] = tile[tx][ty + i * 8];
}

// ---------- sequential scan: one 64-lane wave per (h, i), batched 8t, dbuf ----------
__global__ __launch_bounds__(64) void scan_kernel(const uint2* __restrict__ pk,
                                                  const __hip_bfloat16* __restrict__ vt,
                                                  const float* __restrict__ s2in,
                                                  const float* __restrict__ tf,
                                                  float* __restrict__ wkv,
                                                  float* __restrict__ s2out) {
  const int i = blockIdx.x;   // 0..63
  const int h = blockIdx.y;   // 0..31
  const int j = threadIdx.x;  // 0..63
  const int hb = h * HSZ;
  float s = s2in[((size_t)h * HSZ + i) * HSZ + j];
  const float tfj = tf[hb + j];

  const uint2* pcur = pk + (size_t)h * TLEN * 64 + j;             // step: t*64
  const uint4* vcur = (const uint4*)(vt + (size_t)(hb + i) * TLEN);  // step: t/8
  float* wbase = wkv + hb + i;                                    // step: t*HDIM

  uint2 A[8], B[8];
  uint4 va, vb4;
  float p[8];

#define LOADB(BUF, VV, PTR, VPTR)                         \
  do {                                                    \
    _Pragma("unroll") for (int u = 0; u < 8; u++) BUF[u] = (PTR)[u * 64]; \
    VV = *(VPTR);                                         \
  } while (0)

#define COMPUTE(BUF, VV, T0)                                                   \
  do {                                                                         \
    _Pragma("unroll") for (int u = 0; u < 8; u++) {                            \
      const unsigned wx = BUF[u].x;                                            \
      const float kj = __builtin_bit_cast(float, wx << 16);                    \
      const float rj = __builtin_bit_cast(float, wx & 0xffff0000u);            \
      const float tdj = __builtin_bit_cast(float, BUF[u].y);                   \
      const unsigned vword = ((u >> 1) == 0) ? VV.x                            \
                            : ((u >> 1) == 1) ? VV.y                           \
                            : ((u >> 1) == 2) ? VV.z : VV.w;                   \
      const unsigned vbits = (u & 1) ? (vword & 0xffff0000u) : (vword << 16);  \
      const float vi = __builtin_bit_cast(float, vbits);                       \
      const float kv = vi * kj;                                                \
      p[u] = fmaf(kv, tfj, s) * rj;                                            \
      s = fmaf(s, tdj, kv);                                                    \
    }                                                                          \
    _Pragma("unroll") for (int lv = 0; lv < 6; lv++) {                         \
      _Pragma("unroll") for (int u = 0; u < 8; u++)                            \
        p[u] += __shfl_xor(p[u], 1 << lv, 64);                                 \
    }                                                                          \
    if (j == 0) {                                                              \
      _Pragma("unroll") for (int u = 0; u < 8; u++)                            \
        wbase[(size_t)((T0) + u) * HDIM] = p[u];                               \
    }                                                                          \
  } while (0)

  LOADB(A, va, pcur, vcur);
  for (int t0 = 0; t0 < TLEN; t0 += 16) {
    const uint2* pn1 = pcur + 8 * 64;
    LOADB(B, vb4, pn1, vcur + 1);
    COMPUTE(A, va, t0);
    const uint2* pn2 = pcur + 16 * 64;
    if (t0 + 16 < TLEN) LOADB(A, va, pn2, vcur + 2);
    COMPUTE(B, vb4, t0 + 8);
    pcur = pn2;
    vcur += 2;
  }
#undef LOADB
#undef COMPUTE

  s2out[((size_t)h * HSZ + i) * HSZ + j] = s;
}

// ---------- group norm over HS + scale/bias + gate ----------
__global__ __launch_bounds__(256) void gnorm_kernel(const float* __restrict__ wkv,
                                                    const __hip_bfloat16* __restrict__ gb,
                                                    const float* __restrict__ lnw,
                                                    const float* __restrict__ lnb,
                                                    __hip_bfloat16* __restrict__ yA) {
  const int t = blockIdx.x;
  const int wid = threadIdx.x >> 6, j = threadIdx.x & 63;
  const int h = blockIdx.y * 4 + wid;
  const size_t idx = (size_t)t * HDIM + h * HSZ + j;
  const float v = wkv[idx];
  const float mu = waveRedSum(v) * (1.f / HSZ);
  const float d = v - mu;
  const float var = waveRedSum(d * d) * (1.f / HSZ);
  float y = d * rsqrtf(var + 1e-5f);
  y = y * lnw[h * HSZ + j] + lnb[h * HSZ + j];
  y *= __bfloat162float(gb[idx]);
  yA[idx] = __float2bfloat16(y);
}

extern "C" void kernel_launch(void* const* d_in, const int* in_sizes, int n_in,
                              void* d_out, int out_size, void* d_ws, size_t ws_size,
                              hipStream_t stream) {
  (void)in_sizes; (void)n_in; (void)out_size; (void)ws_size;

  const float* x    = (const float*)d_in[0];
  const float* s1   = (const float*)d_in[1];
  const float* s2   = (const float*)d_in[2];
  const float* ln1w = (const float*)d_in[3];
  const float* ln1b = (const float*)d_in[4];
  const float* tmx  = (const float*)d_in[5];
  const float* tmaa = (const float*)d_in[6];
  const float* w1   = (const float*)d_in[7];
  const float* w2   = (const float*)d_in[8];
  const float* dw1  = (const float*)d_in[9];
  const float* dw2  = (const float*)d_in[10];
  const float* dp   = (const float*)d_in[11];
  const float* tf   = (const float*)d_in[12];
  const float* Wr   = (const float*)d_in[13];
  const float* Wk   = (const float*)d_in[14];
  const float* Wv   = (const float*)d_in[15];
  const float* Wg   = (const float*)d_in[16];
  const float* Wo   = (const float*)d_in[17];
  const float* lnxw = (const float*)d_in[18];
  const float* lnxb = (const float*)d_in[19];

  float* out0  = (float*)d_out;
  float* s1out = out0 + (size_t)TLEN * HDIM;
  float* s2out = s1out + HDIM;

  char* wp = (char*)d_ws;
  size_t off = 0;
  auto carve = [&](size_t bytes) -> void* {
    void* r = wp + off;
    off += (bytes + 255) & ~(size_t)255;
    return r;
  };

  __hip_bfloat16* wrt  = (__hip_bfloat16*)carve((size_t)HDIM * HDIM * 2);
  __hip_bfloat16* wkt  = (__hip_bfloat16*)carve((size_t)HDIM * HDIM * 2);
  __hip_bfloat16* wvt  = (__hip_bfloat16*)carve((size_t)HDIM * HDIM * 2);
  __hip_bfloat16* wgt  = (__hip_bfloat16*)carve((size_t)HDIM * HDIM * 2);
  __hip_bfloat16* wot  = (__hip_bfloat16*)carve((size_t)HDIM * HDIM * 2);
  __hip_bfloat16* w1t  = (__hip_bfloat16*)carve((size_t)160 * HDIM * 2);
  __hip_bfloat16* dw1t = (__hip_bfloat16*)carve((size_t)64 * HDIM * 2);
  __hip_bfloat16* dw2t = (__hip_bfloat16*)carve((size_t)HDIM * 64 * 2);
  float* xl            = (float*)carve((size_t)THE * 4);
  __hip_bfloat16* xxx  = (__hip_bfloat16*)carve((size_t)THE * 2);
  float* t5            = (float*)carve((size_t)TLEN * 160 * 4);
  __hip_bfloat16* x5b  = (__hip_bfloat16*)carve((size_t)5 * THE * 2);
  __hip_bfloat16* rb   = (__hip_bfloat16*)carve((size_t)THE * 2);
  __hip_bfloat16* kb   = (__hip_bfloat16*)carve((size_t)THE * 2);
  __hip_bfloat16* vb   = (__hip_bfloat16*)carve((size_t)THE * 2);
  __hip_bfloat16* gb   = (__hip_bfloat16*)carve((size_t)THE * 2);
  __hip_bfloat16* tw   = (__hip_bfloat16*)carve((size_t)TLEN * 64 * 2);
  float* td            = (float*)carve((size_t)THE * 4);
  float* wkv           = (float*)carve((size_t)THE * 4);
  __hip_bfloat16* yA   = (__hip_bfloat16*)carve((size_t)THE * 2);

  // pk (16MB) + vt (4MB) alias x5b (20MB) — x5b is dead after G5.
  uint2* pk          = (uint2*)x5b;
  __hip_bfloat16* vt = (__hip_bfloat16*)((char*)x5b + (size_t)NHEAD * TLEN * 64 * 8);

  // K0: convert + transpose all GEMM weights to bf16 [N][K]
  TrArgs ta;
  const float* srcs[8] = {Wr, Wk, Wv, Wg, Wo, w1, dw1, dw2};
  __hip_bfloat16* dsts[8] = {wrt, wkt, wvt, wgt, wot, w1t, dw1t, dw2t};
  const int Rs[8] = {HDIM, HDIM, HDIM, HDIM, HDIM, HDIM, HDIM, 64};
  const int Cs[8] = {HDIM, HDIM, HDIM, HDIM, HDIM, 160, 64, HDIM};
  for (int z = 0; z < 8; z++) { ta.src[z] = srcs[z]; ta.dst[z] = dsts[z]; ta.R[z] = Rs[z]; ta.C[z] = Cs[z]; }
  transp_kernel<<<dim3(64, 64, 8), 256, 0, stream>>>(ta);

  // K1: layernorm
  ln1_kernel<<<dim3(TLEN), 256, 0, stream>>>(x, ln1w, ln1b, xl, s1out);

  // K2: token shift -> xxx (bf16)
  tokshift_kernel<<<dim3(TLEN, HDIM / 256), 256, 0, stream>>>(xl, s1, tmx, xxx);

  // G1: t5 = tanh(xxx @ w1)  (M=1024, N=160, K=2048)
  {
    GemmArgs g{};
    g.A[0] = xxx; g.B[0] = w1t; g.C[0] = t5; g.aux[0] = nullptr; g.epi[0] = 2;
    g.M = TLEN; g.N = 160; g.K = HDIM;
    gemm_bt<<<dim3(TLEN / 128, 2, 1), 256, 0, stream>>>(g);
  }

  // K4: mix + x5 (5 planes, bf16)
  mix_kernel<<<dim3(HDIM / 256, TLEN / 8), 256, 0, stream>>>(t5, xl, s1, w2, tmaa, x5b);

  // G2: r, k, v, g  (batched z=4)
  {
    GemmArgs g{};
    g.A[0] = x5b + (size_t)3 * THE; g.B[0] = wrt; g.C[0] = rb; g.epi[0] = 0;
    g.A[1] = x5b + (size_t)1 * THE; g.B[1] = wkt; g.C[1] = kb; g.epi[1] = 0;
    g.A[2] = x5b + (size_t)2 * THE; g.B[2] = wvt; g.C[2] = vb; g.epi[2] = 0;
    g.A[3] = x5b + (size_t)4 * THE; g.B[3] = wgt; g.C[3] = gb; g.epi[3] = 1;
    g.M = TLEN; g.N = HDIM; g.K = HDIM;
    gemm_bt<<<dim3(TLEN / 128, HDIM / 128, 4), 256, 0, stream>>>(g);
  }

  // G4: tw = tanh(mw @ dw1)  (N=64)
  {
    GemmArgs g{};
    g.A[0] = x5b; g.B[0] = dw1t; g.C[0] = tw; g.epi[0] = 3;
    g.M = TLEN; g.N = 64; g.K = HDIM;
    gemm_bt<<<dim3(TLEN / 128, 1, 1), 256, 0, stream>>>(g);
  }

  // G5: td = exp(-exp(clip(tw @ dw2 + p)))  (K=64)
  {
    GemmArgs g{};
    g.A[0] = tw; g.B[0] = dw2t; g.C[0] = td; g.aux[0] = dp; g.epi[0] = 4;
    g.M = TLEN; g.N = HDIM; g.K = 64;
    gemm_bt<<<dim3(TLEN / 128, HDIM / 128, 1), 256, 0, stream>>>(g);
  }

  // K5a: pack k,r,td -> pk ; K5b: transpose v -> vt
  repack_kernel<<<dim3((NHEAD * TLEN * 64) / 256), 256, 0, stream>>>(kb, rb, td, pk);
  vtr_kernel<<<dim3(HDIM / 32, TLEN / 32), 256, 0, stream>>>(vb, vt);

  // K6: recurrent scan
  scan_kernel<<<dim3(HSZ, NHEAD), 64, 0, stream>>>(pk, vt, s2, tf, wkv, s2out);

  // K7: group-norm + gate -> yA (bf16)
  gnorm_kernel<<<dim3(TLEN, NHEAD / 4), 256, 0, stream>>>(wkv, gb, lnxw, lnxb, yA);

  // G6: out = x + yA @ W_o
  {
    GemmArgs g{};
    g.A[0] = yA; g.B[0] = wot; g.C[0] = out0; g.aux[0] = x; g.epi[0] = 5;
    g.M = TLEN; g.N = HDIM; g.K = HDIM;
    gemm_bt<<<dim3(TLEN / 128, HDIM / 128, 1), 256, 0, stream>>>(g);
  }
}

// Round 3
// 520.923 us; speedup vs baseline: 1.8326x; 1.0037x over previous
//
#include <hip/hip_runtime.h>
#include <hip/hip_bf16.h>
#include <math.h>

#define TLEN 1024
#define HDIM 2048
#define NHEAD 32
#define HSZ 64
#define THE (TLEN * HDIM)

typedef __attribute__((ext_vector_type(8))) short bf16x8;
typedef __attribute__((ext_vector_type(4))) float f32x4;

__device__ __forceinline__ float waveRedSum(float v) {
#pragma unroll
  for (int off = 32; off > 0; off >>= 1) v += __shfl_xor(v, off, 64);
  return v;
}

__device__ __forceinline__ void gll16(const __hip_bfloat16* g, __hip_bfloat16* l) {
  __builtin_amdgcn_global_load_lds(
      (const __attribute__((address_space(1))) void*)g,
      (__attribute__((address_space(3))) void*)l, 16, 0, 0);
}

// ---------- weight convert + transpose: src f32 [R][C] -> dst bf16 [C][R] ----------
struct TrArgs {
  const float* src[8];
  __hip_bfloat16* dst[8];
  int R[8];
  int C[8];
};

__global__ __launch_bounds__(256) void transp_kernel(TrArgs ta) {
  const int z = blockIdx.z;
  const int R = ta.R[z], C = ta.C[z];
  const int c0 = blockIdx.x * 32, r0 = blockIdx.y * 32;
  if (c0 >= C || r0 >= R) return;
  __shared__ float tile[32][33];
  const int tx = threadIdx.x & 31, ty = threadIdx.x >> 5;
  const float* src = ta.src[z];
  __hip_bfloat16* dst = ta.dst[z];
#pragma unroll
  for (int i = 0; i < 4; i++)
    tile[ty + i * 8][tx] = src[(size_t)(r0 + ty + i * 8) * C + c0 + tx];
  __syncthreads();
#pragma unroll
  for (int i = 0; i < 4; i++)
    dst[(size_t)(c0 + ty + i * 8) * R + r0 + tx] = __float2bfloat16(tile[tx][ty + i * 8]);
}

// ---------- LayerNorm (row) + state1_out ----------
__global__ __launch_bounds__(256) void ln1_kernel(const float* __restrict__ x,
                                                  const float* __restrict__ w,
                                                  const float* __restrict__ b,
                                                  float* __restrict__ xl,
                                                  float* __restrict__ s1out) {
  const int t = blockIdx.x;
  const int tid = threadIdx.x;
  const int wid = tid >> 6, lane = tid & 63;
  const float4* xr = (const float4*)(x + (size_t)t * HDIM);
  float4 a = xr[tid];
  float4 c = xr[tid + 256];
  float va[8] = {a.x, a.y, a.z, a.w, c.x, c.y, c.z, c.w};
  float sum = 0.f;
#pragma unroll
  for (int i = 0; i < 8; i++) sum += va[i];
  sum = waveRedSum(sum);
  __shared__ float red[8];
  if (lane == 0) red[wid] = sum;
  __syncthreads();
  const float mu = (red[0] + red[1] + red[2] + red[3]) * (1.f / HDIM);
  float vs = 0.f;
#pragma unroll
  for (int i = 0; i < 8; i++) { float d = va[i] - mu; vs += d * d; }
  vs = waveRedSum(vs);
  if (lane == 0) red[4 + wid] = vs;
  __syncthreads();
  const float rstd = rsqrtf((red[4] + red[5] + red[6] + red[7]) * (1.f / HDIM) + 1e-5f);
  float* xrow = xl + (size_t)t * HDIM;
#pragma unroll
  for (int i = 0; i < 8; i++) {
    const int idx = (i < 4) ? (4 * tid + i) : (1024 + 4 * tid + (i - 4));
    const float o = (va[i] - mu) * rstd * w[idx] + b[idx];
    xrow[idx] = o;
    if (t == TLEN - 1) s1out[idx] = o;
  }
}

// ---------- token shift: xxx = xl + (past - xl) * time_maa_x ----------
__global__ __launch_bounds__(256) void tokshift_kernel(const float* __restrict__ xl,
                                                       const float* __restrict__ s1,
                                                       const float* __restrict__ tmx,
                                                       __hip_bfloat16* __restrict__ xxx) {
  const int t = blockIdx.x;
  const int h = blockIdx.y * 256 + threadIdx.x;
  const float cur = xl[(size_t)t * HDIM + h];
  const float past = (t > 0) ? xl[(size_t)(t - 1) * HDIM + h] : s1[h];
  xxx[(size_t)t * HDIM + h] = __float2bfloat16(cur + (past - cur) * tmx[h]);
}

// ---------- mix: x5[f] = xl + sx * (t5[f] @ w2[f] + time_maa[f]) ----------
__global__ __launch_bounds__(256) void mix_kernel(const float* __restrict__ t5,
                                                  const float* __restrict__ xl,
                                                  const float* __restrict__ s1,
                                                  const float* __restrict__ w2,
                                                  const float* __restrict__ maa,
                                                  __hip_bfloat16* __restrict__ x5b) {
  const int h = blockIdx.x * 256 + threadIdx.x;
  const int t0 = blockIdx.y * 8;
  __shared__ float t5L[8 * 160];
  for (int i = threadIdx.x; i < 8 * 160; i += 256) {
    const int rr = i / 160, cc = i - rr * 160;
    t5L[i] = t5[(size_t)(t0 + rr) * 160 + cc];
  }
  __syncthreads();
  float mixv[8][5];
#pragma unroll
  for (int ts = 0; ts < 8; ts++)
#pragma unroll
    for (int f = 0; f < 5; f++) mixv[ts][f] = 0.f;
#pragma unroll
  for (int f = 0; f < 5; f++) {
#pragma unroll 4
    for (int m = 0; m < 32; m++) {
      const float w2v = w2[(size_t)(f * 32 + m) * HDIM + h];
#pragma unroll
      for (int ts = 0; ts < 8; ts++) mixv[ts][f] += t5L[ts * 160 + f * 32 + m] * w2v;
    }
  }
#pragma unroll
  for (int ts = 0; ts < 8; ts++) {
    const int t = t0 + ts;
    const float cur = xl[(size_t)t * HDIM + h];
    const float past = (t > 0) ? xl[(size_t)(t - 1) * HDIM + h] : s1[h];
    const float sx = past - cur;
#pragma unroll
    for (int f = 0; f < 5; f++) {
      const float v = cur + sx * (mixv[ts][f] + maa[(size_t)f * HDIM + h]);
      x5b[(size_t)f * THE + (size_t)t * HDIM + h] = __float2bfloat16(v);
    }
  }
}

// ---------- batched MFMA GEMM: C[z] = epi( A[z](MxK) @ Bt[z](NxK)^T ) ----------
// epi: 0=bf16 none, 1=bf16 silu, 2=f32 tanh, 3=bf16 tanh, 4=f32 td(+p,clip,exp-exp), 5=f32 +residual
struct GemmArgs {
  const __hip_bfloat16* A[4];
  const __hip_bfloat16* B[4];
  void* C[4];
  const float* aux[4];
  int epi[4];
  int M, N, K;
};

__global__ __launch_bounds__(256) void gemm_bt(GemmArgs ga) {
  const int z = blockIdx.z;
  const __hip_bfloat16* __restrict__ A = ga.A[z];
  const __hip_bfloat16* __restrict__ Bt = ga.B[z];
  const int N = ga.N, K = ga.K;
  const int epi = ga.epi[z];
  const float* __restrict__ aux = ga.aux[z];
  void* Cz = ga.C[z];

  __shared__ __align__(16) __hip_bfloat16 As[128 * 32];
  __shared__ __align__(16) __hip_bfloat16 Bs[128 * 32];

  const int tid = threadIdx.x;
  const int wid = tid >> 6;
  const int lane = tid & 63;

  // XCD-aware swizzle for the 8x16 grids: cluster all 8 m-blocks of one
  // n-panel onto a single XCD so the B panel stays L2-resident.
  int bx = blockIdx.x, by = blockIdx.y;
  if (gridDim.x == 8 && gridDim.y == 16) {
    const int flat = bx + 8 * by;  // 0..127
    const int xcd = flat & 7, rem = flat >> 3;
    bx = rem & 7;
    by = xcd + 8 * (rem >> 3);
  }
  const int m0 = bx * 128;
  const int n0 = by * 128;
  const int wr = wid >> 1, wc = wid & 1;

  const int rsub = lane >> 2;   // 0..15
  const int chunk = lane & 3;   // 0..3
  const int ca = 2 * wid;       // this wave's staging calls: ca, ca+1

  const int arow0 = ca * 16 + rsub;
  const int arow1 = arow0 + 16;
  int brow0 = n0 + arow0; if (brow0 > N - 1) brow0 = N - 1;
  int brow1 = n0 + arow1; if (brow1 > N - 1) brow1 = N - 1;

  const __hip_bfloat16* aSrc0 = A + (size_t)(m0 + arow0) * K + chunk * 8;
  const __hip_bfloat16* aSrc1 = A + (size_t)(m0 + arow1) * K + chunk * 8;
  const __hip_bfloat16* bSrc0 = Bt + (size_t)brow0 * K + chunk * 8;
  const __hip_bfloat16* bSrc1 = Bt + (size_t)brow1 * K + chunk * 8;

  f32x4 acc[4][4];
#pragma unroll
  for (int m = 0; m < 4; m++)
#pragma unroll
    for (int n = 0; n < 4; n++) acc[m][n] = 0.f;

  const int lr = lane & 15;
  const int lk8 = (lane >> 4) * 8;
  const int aoff = (wr * 64 + lr) * 32 + lk8;
  const int boff = (wc * 64 + lr) * 32 + lk8;

  for (int kt = 0; kt < K; kt += 32) {
    gll16(aSrc0 + kt, &As[ca * 512]);
    gll16(aSrc1 + kt, &As[ca * 512 + 512]);
    gll16(bSrc0 + kt, &Bs[ca * 512]);
    gll16(bSrc1 + kt, &Bs[ca * 512 + 512]);
    __syncthreads();
    bf16x8 af[4], bfv[4];
#pragma unroll
    for (int m = 0; m < 4; m++) af[m] = *(const bf16x8*)&As[aoff + m * 16 * 32];
#pragma unroll
    for (int n = 0; n < 4; n++) bfv[n] = *(const bf16x8*)&Bs[boff + n * 16 * 32];
#pragma unroll
    for (int m = 0; m < 4; m++)
#pragma unroll
      for (int n = 0; n < 4; n++)
        acc[m][n] = __builtin_amdgcn_mfma_f32_16x16x32_bf16(af[m], bfv[n], acc[m][n], 0, 0, 0);
    __syncthreads();
  }

  const int r4 = (lane >> 4) * 4;
#pragma unroll
  for (int m = 0; m < 4; m++) {
#pragma unroll
    for (int n = 0; n < 4; n++) {
      const int gn = n0 + wc * 64 + n * 16 + lr;
      if (gn < N) {
#pragma unroll
        for (int r = 0; r < 4; r++) {
          const int gm = m0 + wr * 64 + m * 16 + r4 + r;
          const size_t idx = (size_t)gm * N + gn;
          const float v = acc[m][n][r];
          switch (epi) {
            case 0: ((__hip_bfloat16*)Cz)[idx] = __float2bfloat16(v); break;
            case 1: ((__hip_bfloat16*)Cz)[idx] = __float2bfloat16(v / (1.f + expf(-v))); break;
            case 2: ((float*)Cz)[idx] = tanhf(v); break;
            case 3: ((__hip_bfloat16*)Cz)[idx] = __float2bfloat16(tanhf(v)); break;
            case 4: {
              float wv = v + aux[gn];
              wv = fminf(fmaxf(wv, -9.72f), 2.27f);
              ((float*)Cz)[idx] = expf(-expf(wv));
            } break;
            case 5: ((float*)Cz)[idx] = v + aux[idx]; break;
          }
        }
      }
    }
  }
}

// ---------- repack k,r,td into 8B records: pk[h][t][j] = {k|r<<16, td} ----------
__global__ __launch_bounds__(256) void repack_kernel(const __hip_bfloat16* __restrict__ kb,
                                                     const __hip_bfloat16* __restrict__ rb,
                                                     const float* __restrict__ td,
                                                     uint2* __restrict__ pk) {
  const int idx = blockIdx.x * 256 + threadIdx.x;  // [h][t][j]
  const int j = idx & 63;
  const int t = (idx >> 6) & (TLEN - 1);
  const int h = idx >> 16;
  const size_t src = (size_t)t * HDIM + h * HSZ + j;
  uint2 o;
  const unsigned kk = *(const unsigned short*)&kb[src];
  const unsigned rr = *(const unsigned short*)&rb[src];
  o.x = kk | (rr << 16);
  o.y = __builtin_bit_cast(unsigned, td[src]);
  pk[idx] = o;
}

// ---------- v transpose: vb [TLEN][HDIM] bf16 -> vt [HDIM][TLEN] bf16 ----------
__global__ __launch_bounds__(256) void vtr_kernel(const __hip_bfloat16* __restrict__ vb,
                                                  __hip_bfloat16* __restrict__ vt) {
  __shared__ unsigned short tile[32][33];
  const int c0 = blockIdx.x * 32;  // HDIM
  const int r0 = blockIdx.y * 32;  // TLEN
  const int tx = threadIdx.x & 31, ty = threadIdx.x >> 5;
#pragma unroll
  for (int i = 0; i < 4; i++)
    tile[ty + i * 8][tx] = *(const unsigned short*)&vb[(size_t)(r0 + ty + i * 8) * HDIM + c0 + tx];
  __syncthreads();
#pragma unroll
  for (int i = 0; i < 4; i++)
    *(unsigned short*)&vt[(size_t)(c0 + ty + i * 8) * TLEN + r0 + tx] = tile[tx][ty + i * 8];
}

// ---------- sequential scan: one wave per (h,i); 4-deep prefetch; XCD-swizzled ----------
__global__ __launch_bounds__(64) void scan_kernel(const uint2* __restrict__ pk,
                                                  const __hip_bfloat16* __restrict__ vt,
                                                  const float* __restrict__ s2in,
                                                  const float* __restrict__ tf,
                                                  float* __restrict__ wkv,
                                                  float* __restrict__ s2out) {
  // Swizzle so each XCD (blockIdx%8 round-robin) owns 4 heads entirely:
  // pk working set per XCD = 4 heads * 512KB = 2MB -> L2 resident.
  const int flat = blockIdx.x;
  const int xcd = flat & 7;
  const int inner = flat >> 3;        // 0..255
  const int h = xcd * 4 + (inner >> 6);
  const int i = inner & 63;
  const int j = threadIdx.x;          // 0..63
  const int hb = h * HSZ;
  float s = s2in[((size_t)h * HSZ + i) * HSZ + j];
  const float tfj = tf[hb + j];

  const uint2* pbase = pk + (size_t)h * TLEN * 64 + j;
  const uint4* vbase = (const uint4*)(vt + (size_t)(hb + i) * TLEN);
  float* wbase = wkv + hb + i;

  uint2 A[8], B[8], C8[8], D8[8];
  uint4 va, vb4, vc4, vd4;
  float p[8];

#define LOADB(BUF, VV, BT)                                                    \
  do {                                                                        \
    int bc_ = (BT); if (bc_ > 127) bc_ = 127;                                 \
    const uint2* pp_ = pbase + (size_t)bc_ * 512;                             \
    _Pragma("unroll") for (int u = 0; u < 8; u++) BUF[u] = pp_[u * 64];       \
    VV = vbase[bc_];                                                          \
  } while (0)

#define COMPUTE(BUF, VV, T0)                                                   \
  do {                                                                         \
    _Pragma("unroll") for (int u = 0; u < 8; u++) {                            \
      const unsigned wx = BUF[u].x;                                            \
      const float kj = __builtin_bit_cast(float, wx << 16);                    \
      const float rj = __builtin_bit_cast(float, wx & 0xffff0000u);            \
      const float tdj = __builtin_bit_cast(float, BUF[u].y);                   \
      const unsigned vword = ((u >> 1) == 0) ? VV.x                            \
                            : ((u >> 1) == 1) ? VV.y                           \
                            : ((u >> 1) == 2) ? VV.z : VV.w;                   \
      const unsigned vbits = (u & 1) ? (vword & 0xffff0000u) : (vword << 16);  \
      const float vi = __builtin_bit_cast(float, vbits);                       \
      const float kv = vi * kj;                                                \
      p[u] = fmaf(kv, tfj, s) * rj;                                            \
      s = fmaf(s, tdj, kv);                                                    \
    }                                                                          \
    _Pragma("unroll") for (int lv = 0; lv < 6; lv++) {                         \
      _Pragma("unroll") for (int u = 0; u < 8; u++)                            \
        p[u] += __shfl_xor(p[u], 1 << lv, 64);                                 \
    }                                                                          \
    if (j == 0) {                                                              \
      _Pragma("unroll") for (int u = 0; u < 8; u++)                            \
        wbase[(size_t)((T0) + u) * HDIM] = p[u];                               \
    }                                                                          \
  } while (0)

  LOADB(A, va, 0);
  LOADB(B, vb4, 1);
  LOADB(C8, vc4, 2);
  for (int bt = 0; bt < 128; bt += 4) {
    LOADB(D8, vd4, bt + 3); COMPUTE(A, va, bt * 8);
    LOADB(A, va, bt + 4);   COMPUTE(B, vb4, (bt + 1) * 8);
    LOADB(B, vb4, bt + 5);  COMPUTE(C8, vc4, (bt + 2) * 8);
    LOADB(C8, vc4, bt + 6); COMPUTE(D8, vd4, (bt + 3) * 8);
  }
#undef LOADB
#undef COMPUTE

  s2out[((size_t)h * HSZ + i) * HSZ + j] = s;
}

// ---------- group norm over HS + scale/bias + gate ----------
__global__ __launch_bounds__(256) void gnorm_kernel(const float* __restrict__ wkv,
                                                    const __hip_bfloat16* __restrict__ gb,
                                                    const float* __restrict__ lnw,
                                                    const float* __restrict__ lnb,
                                                    __hip_bfloat16* __restrict__ yA) {
  const int t = blockIdx.x;
  const int wid = threadIdx.x >> 6, j = threadIdx.x & 63;
  const int h = blockIdx.y * 4 + wid;
  const size_t idx = (size_t)t * HDIM + h * HSZ + j;
  const float v = wkv[idx];
  const float mu = waveRedSum(v) * (1.f / HSZ);
  const float d = v - mu;
  const float var = waveRedSum(d * d) * (1.f / HSZ);
  float y = d * rsqrtf(var + 1e-5f);
  y = y * lnw[h * HSZ + j] + lnb[h * HSZ + j];
  y *= __bfloat162float(gb[idx]);
  yA[idx] = __float2bfloat16(y);
}

extern "C" void kernel_launch(void* const* d_in, const int* in_sizes, int n_in,
                              void* d_out, int out_size, void* d_ws, size_t ws_size,
                              hipStream_t stream) {
  (void)in_sizes; (void)n_in; (void)out_size; (void)ws_size;

  const float* x    = (const float*)d_in[0];
  const float* s1   = (const float*)d_in[1];
  const float* s2   = (const float*)d_in[2];
  const float* ln1w = (const float*)d_in[3];
  const float* ln1b = (const float*)d_in[4];
  const float* tmx  = (const float*)d_in[5];
  const float* tmaa = (const float*)d_in[6];
  const float* w1   = (const float*)d_in[7];
  const float* w2   = (const float*)d_in[8];
  const float* dw1  = (const float*)d_in[9];
  const float* dw2  = (const float*)d_in[10];
  const float* dp   = (const float*)d_in[11];
  const float* tf   = (const float*)d_in[12];
  const float* Wr   = (const float*)d_in[13];
  const float* Wk   = (const float*)d_in[14];
  const float* Wv   = (const float*)d_in[15];
  const float* Wg   = (const float*)d_in[16];
  const float* Wo   = (const float*)d_in[17];
  const float* lnxw = (const float*)d_in[18];
  const float* lnxb = (const float*)d_in[19];

  float* out0  = (float*)d_out;
  float* s1out = out0 + (size_t)TLEN * HDIM;
  float* s2out = s1out + HDIM;

  char* wp = (char*)d_ws;
  size_t off = 0;
  auto carve = [&](size_t bytes) -> void* {
    void* r = wp + off;
    off += (bytes + 255) & ~(size_t)255;
    return r;
  };

  __hip_bfloat16* wrt  = (__hip_bfloat16*)carve((size_t)HDIM * HDIM * 2);
  __hip_bfloat16* wkt  = (__hip_bfloat16*)carve((size_t)HDIM * HDIM * 2);
  __hip_bfloat16* wvt  = (__hip_bfloat16*)carve((size_t)HDIM * HDIM * 2);
  __hip_bfloat16* wgt  = (__hip_bfloat16*)carve((size_t)HDIM * HDIM * 2);
  __hip_bfloat16* wot  = (__hip_bfloat16*)carve((size_t)HDIM * HDIM * 2);
  __hip_bfloat16* w1t  = (__hip_bfloat16*)carve((size_t)160 * HDIM * 2);
  __hip_bfloat16* dw1t = (__hip_bfloat16*)carve((size_t)64 * HDIM * 2);
  __hip_bfloat16* dw2t = (__hip_bfloat16*)carve((size_t)HDIM * 64 * 2);
  float* xl            = (float*)carve((size_t)THE * 4);
  __hip_bfloat16* xxx  = (__hip_bfloat16*)carve((size_t)THE * 2);
  float* t5            = (float*)carve((size_t)TLEN * 160 * 4);
  __hip_bfloat16* x5b  = (__hip_bfloat16*)carve((size_t)5 * THE * 2);
  __hip_bfloat16* rb   = (__hip_bfloat16*)carve((size_t)THE * 2);
  __hip_bfloat16* kb   = (__hip_bfloat16*)carve((size_t)THE * 2);
  __hip_bfloat16* vb   = (__hip_bfloat16*)carve((size_t)THE * 2);
  __hip_bfloat16* gb   = (__hip_bfloat16*)carve((size_t)THE * 2);
  __hip_bfloat16* tw   = (__hip_bfloat16*)carve((size_t)TLEN * 64 * 2);
  float* td            = (float*)carve((size_t)THE * 4);
  float* wkv           = (float*)carve((size_t)THE * 4);
  __hip_bfloat16* yA   = (__hip_bfloat16*)carve((size_t)THE * 2);

  // pk (16MB) + vt (4MB) alias x5b (20MB) — x5b is dead after G5.
  uint2* pk          = (uint2*)x5b;
  __hip_bfloat16* vt = (__hip_bfloat16*)((char*)x5b + (size_t)NHEAD * TLEN * 64 * 8);

  // K0: convert + transpose all GEMM weights to bf16 [N][K]
  TrArgs ta;
  const float* srcs[8] = {Wr, Wk, Wv, Wg, Wo, w1, dw1, dw2};
  __hip_bfloat16* dsts[8] = {wrt, wkt, wvt, wgt, wot, w1t, dw1t, dw2t};
  const int Rs[8] = {HDIM, HDIM, HDIM, HDIM, HDIM, HDIM, HDIM, 64};
  const int Cs[8] = {HDIM, HDIM, HDIM, HDIM, HDIM, 160, 64, HDIM};
  for (int z = 0; z < 8; z++) { ta.src[z] = srcs[z]; ta.dst[z] = dsts[z]; ta.R[z] = Rs[z]; ta.C[z] = Cs[z]; }
  transp_kernel<<<dim3(64, 64, 8), 256, 0, stream>>>(ta);

  // K1: layernorm
  ln1_kernel<<<dim3(TLEN), 256, 0, stream>>>(x, ln1w, ln1b, xl, s1out);

  // K2: token shift -> xxx (bf16)
  tokshift_kernel<<<dim3(TLEN, HDIM / 256), 256, 0, stream>>>(xl, s1, tmx, xxx);

  // G1: t5 = tanh(xxx @ w1)  (M=1024, N=160, K=2048)
  {
    GemmArgs g{};
    g.A[0] = xxx; g.B[0] = w1t; g.C[0] = t5; g.aux[0] = nullptr; g.epi[0] = 2;
    g.M = TLEN; g.N = 160; g.K = HDIM;
    gemm_bt<<<dim3(TLEN / 128, 2, 1), 256, 0, stream>>>(g);
  }

  // K4: mix + x5 (5 planes, bf16)
  mix_kernel<<<dim3(HDIM / 256, TLEN / 8), 256, 0, stream>>>(t5, xl, s1, w2, tmaa, x5b);

  // G2: r, k, v, g  (batched z=4)
  {
    GemmArgs g{};
    g.A[0] = x5b + (size_t)3 * THE; g.B[0] = wrt; g.C[0] = rb; g.epi[0] = 0;
    g.A[1] = x5b + (size_t)1 * THE; g.B[1] = wkt; g.C[1] = kb; g.epi[1] = 0;
    g.A[2] = x5b + (size_t)2 * THE; g.B[2] = wvt; g.C[2] = vb; g.epi[2] = 0;
    g.A[3] = x5b + (size_t)4 * THE; g.B[3] = wgt; g.C[3] = gb; g.epi[3] = 1;
    g.M = TLEN; g.N = HDIM; g.K = HDIM;
    gemm_bt<<<dim3(TLEN / 128, HDIM / 128, 4), 256, 0, stream>>>(g);
  }

  // G4: tw = tanh(mw @ dw1)  (N=64)
  {
    GemmArgs g{};
    g.A[0] = x5b; g.B[0] = dw1t; g.C[0] = tw; g.epi[0] = 3;
    g.M = TLEN; g.N = 64; g.K = HDIM;
    gemm_bt<<<dim3(TLEN / 128, 1, 1), 256, 0, stream>>>(g);
  }

  // G5: td = exp(-exp(clip(tw @ dw2 + p)))  (K=64)
  {
    GemmArgs g{};
    g.A[0] = tw; g.B[0] = dw2t; g.C[0] = td; g.aux[0] = dp; g.epi[0] = 4;
    g.M = TLEN; g.N = HDIM; g.K = 64;
    gemm_bt<<<dim3(TLEN / 128, HDIM / 128, 1), 256, 0, stream>>>(g);
  }

  // K5a: pack k,r,td -> pk ; K5b: transpose v -> vt
  repack_kernel<<<dim3((NHEAD * TLEN * 64) / 256), 256, 0, stream>>>(kb, rb, td, pk);
  vtr_kernel<<<dim3(HDIM / 32, TLEN / 32), 256, 0, stream>>>(vb, vt);

  // K6: recurrent scan
  scan_kernel<<<dim3(NHEAD * HSZ), 64, 0, stream>>>(pk, vt, s2, tf, wkv, s2out);

  // K7: group-norm + gate -> yA (bf16)
  gnorm_kernel<<<dim3(TLEN, NHEAD / 4), 256, 0, stream>>>(wkv, gb, lnxw, lnxb, yA);

  // G6: out = x + yA @ W_o
  {
    GemmArgs g{};
    g.A[0] = yA; g.B[0] = wot; g.C[0] = out0; g.aux[0] = x; g.epi[0] = 5;
    g.M = TLEN; g.N = HDIM; g.K = HDIM;
    gemm_bt<<<dim3(TLEN / 128, HDIM / 128, 1), 256, 0, stream>>>(g);
  }
}